// Round 2
// baseline (253.303 us; speedup 1.0000x reference)
//
#include <hip/hip_runtime.h>
#include <hip/hip_bf16.h>

#define BB 32
#define HH 56
#define WW 56
#define CC 256
#define NPIX (BB*HH*WW)   // 100352
#define GRP 32
#define GSZ (NPIX*8)      // 802816 bf16 elems per group slice
#define EPS 1e-5f

typedef short bf16x8 __attribute__((ext_vector_type(8)));   // 8 bf16 = 4 VGPRs
typedef float f32x4  __attribute__((ext_vector_type(4)));

__device__ __forceinline__ unsigned short f2bf(float f) {
    __hip_bfloat16 h = __float2bfloat16(f);
    return *reinterpret_cast<unsigned short*>(&h);
}

// ws layout:
//   float stats[512]   : byte 0      (sum[256], sumsq[256])
//   float ss[512]      : byte 2048   (scale[256], shift[256])
//   bf16  y[B*H*W*256] : byte 4096                (51.4 MB)
//   bf16  xg[32][NPIX][8] : byte 4096+51380224    (51.4 MB, group-major x)

__global__ void k0_zero(float* stats) { stats[threadIdx.x] = 0.f; }

// Relayout + downconvert: x f32 NHWC (1KB/pixel) -> xg bf16 group-major
// ([g][pix][8ch], 16B/pixel/group). Both sides DRAM-linear:
//  phase1 reads 1KB-contiguous per 32 lanes; phase2 writes 512B-contiguous
//  runs per 32 lanes (one group stream each). LDS bridge, stride 260 shorts
//  (520B): phase2 reads land 1-bank stride (conflict-free), phase1 writes
//  4-way (one ds op, acceptable).
__global__ __launch_bounds__(256) void k_pre(
    const float* __restrict__ x, __hip_bfloat16* __restrict__ xg)
{
    __shared__ unsigned short lx[32*260];   // 32 pixels x 260 shorts = 16.6 KB
    const int t  = threadIdx.x;
    const int P0 = blockIdx.x * 32;

    #pragma unroll
    for (int r = 0; r < 8; ++r) {           // 32 pixels x 64 float4-chunks
        const int id  = r*256 + t;          // pix = id>>6, c4 = id&63
        const int pix = id >> 6;
        const int c4  = id & 63;
        float4 v = *(const float4*)(x + (size_t)(P0+pix)*CC + c4*4);
        ushort4 s;
        s.x = f2bf(v.x); s.y = f2bf(v.y); s.z = f2bf(v.z); s.w = f2bf(v.w);
        *(ushort4*)(lx + pix*260 + c4*4) = s;
    }
    __syncthreads();
    #pragma unroll
    for (int r = 0; r < 4; ++r) {           // 32 groups x 32 pixels
        const int oid = r*256 + t;          // pl = oid&31, g = oid>>5
        const int pl  = oid & 31;
        const int g   = oid >> 5;
        ushort4 a = *(const ushort4*)(lx + pl*260 + g*8);
        ushort4 c = *(const ushort4*)(lx + pl*260 + g*8 + 4);
        __hip_bfloat16* dst = xg + (size_t)g*GSZ + (size_t)(P0+pl)*8;
        *(ushort4*)dst       = a;
        *(ushort4*)(dst + 4) = c;
    }
}

// Grouped conv via bf16 MFMA. Block: one group-pair (16 out-ch), one 8-row
// band, one batch image. K packed [g0 taps + pad][g1 taps + pad] = 160
// -> 5 x mfma_f32_16x16x32_bf16 with block-diagonal operand.
// Staging now reads xg (group-major bf16): per (row,group) a ~900B
// contiguous run -> DRAM page friendly (was 64B per 1KB stride = activate-
// limited ~2TB/s). No f32->bf16 conversion in this kernel anymore.
// LDS writes are ds_write_b128 at 48B/pixel stride: 8 consecutive cols
// cover all 32 banks exactly once -> conflict-free.
__global__ __launch_bounds__(256, 5) void k1_conv(
    const __hip_bfloat16* __restrict__ xg, const float* __restrict__ wgt,
    __hip_bfloat16* __restrict__ y, float* __restrict__ stats)
{
    __shared__ unsigned short xt[10*58*24];   // bf16 tile, padded stride (27.8 KB)
    __shared__ float bsum[16], bsq[16];

    const int gp = blockIdx.x;      // group pair 0..15 (channels gp*16..+16)
    const int hb = blockIdx.y;      // 8-row band 0..6
    const int b  = blockIdx.z;
    const int t  = threadIdx.x;
    const int h0 = hb * 8;

    if (t < 16) { bsum[t] = 0.f; bsq[t] = 0.f; }

    // ---- stage xg tile: 10 rows x 2 groups x 58 cols, one uint4 per elem
    #pragma unroll
    for (int j = 0; j < 5; ++j) {
        const int e   = j*256 + t;        // < 1160 valid
        const int col = e % 58;           // const divisor -> magic mul
        const int rg  = e / 58;           // 0..19
        const int row = rg >> 1;
        const int g   = rg & 1;
        const int hh  = h0 - 1 + row;
        const int wc  = col - 1;
        uint4 v = make_uint4(0u, 0u, 0u, 0u);
        if (e < 1160 && (unsigned)hh < HH && (unsigned)wc < WW)
            v = *(const uint4*)(xg + (size_t)(gp*2+g)*GSZ
                                   + (size_t)((b*HH + hh)*WW + wc)*8);
        if (e < 1160)
            *(uint4*)(xt + (row*58 + col)*24 + g*8) = v;
    }

    const int lane = t & 63;
    const int rp   = t >> 6;              // wave id = row-pair 0..3
    const int n    = lane & 15;           // A row (local out-ch)
    const int q    = lane >> 4;           // K-octet

    // ---- A-fragments (weights) straight from global: octet o = one tap of
    // one group-half, elements = the 8 in-ch of that tap (stride 1KB, L1-hit).
    bf16x8 wfrag[5];
    #pragma unroll
    for (int s = 0; s < 5; ++s) {
        const int o   = s*4 + q;          // octet 0..19
        const int g   = (o >= 10);
        const int tap = o - g*10;
        bf16x8 f = {0,0,0,0,0,0,0,0};
        if (tap < 9 && (n >> 3) == g) {
            #pragma unroll
            for (int e = 0; e < 8; ++e)
                f[e] = (short)f2bf(wgt[(tap*8 + e)*CC + gp*16 + n]);
        }
        wfrag[s] = f;
    }

    __syncthreads();

    const int m    = lane & 15;           // B col (pixel in 2x8 tile)
    const int rowr = rp*2 + (m >> 3);     // tile row of pixel (0..7)
    const int colb = m & 7;               // tile col within 8-col tile

    // B-fragment LDS offsets per K-step (lane octet -> tap,g)
    int aoff[5];
    #pragma unroll
    for (int s = 0; s < 5; ++s) {
        int o  = s*4 + q;
        int g  = (o >= 10);
        int tp = o - g*10;
        if (tp == 9) tp = 0;              // pad octet: A is zero, addr dontcare
        int dh = tp / 3, dw = tp - dh*3;
        aoff[s] = ((rowr + dh)*58 + colb + dw)*24 + g*8;
    }

    const int h = h0 + rowr;
    const size_t pixbase = ((size_t)(b*HH + h))*WW;
    float lsum[4] = {0.f, 0.f, 0.f, 0.f};
    float lsq[4]  = {0.f, 0.f, 0.f, 0.f};

    #pragma unroll 2
    for (int ct = 0; ct < 7; ++ct) {      // 7 col-tiles of 8 pixels
        f32x4 acc = {0.f, 0.f, 0.f, 0.f};
        #pragma unroll
        for (int s = 0; s < 5; ++s) {
            bf16x8 af = *(const bf16x8*)(xt + aoff[s] + ct*192);
            acc = __builtin_amdgcn_mfma_f32_16x16x32_bf16(wfrag[s], af, acc, 0, 0, 0);
        }
        // lane holds channels gp*16 + q*4 + 0..3 of pixel (h, ct*8+colb)
        ushort4 st;
        st.x = f2bf(acc[0]); st.y = f2bf(acc[1]);
        st.z = f2bf(acc[2]); st.w = f2bf(acc[3]);
        *(ushort4*)(y + (pixbase + ct*8 + colb)*CC + gp*16 + q*4) = st;
        #pragma unroll
        for (int i = 0; i < 4; ++i) {
            lsum[i] += acc[i];
            lsq[i]  += acc[i]*acc[i];
        }
    }

    // reduce over the 16 lanes sharing this channel quad (same q)
    #pragma unroll
    for (int d = 8; d >= 1; d >>= 1) {
        #pragma unroll
        for (int i = 0; i < 4; ++i) {
            lsum[i] += __shfl_xor(lsum[i], d);
            lsq[i]  += __shfl_xor(lsq[i],  d);
        }
    }
    if (m == 0) {
        #pragma unroll
        for (int i = 0; i < 4; ++i) {
            atomicAdd(&bsum[q*4 + i], lsum[i]);
            atomicAdd(&bsq[q*4 + i],  lsq[i]);
        }
    }
    __syncthreads();
    if (t < 16) {
        atomicAdd(&stats[gp*16 + t],       bsum[t]);
        atomicAdd(&stats[256 + gp*16 + t], bsq[t]);
    }
}

__global__ void k2_finalize(const float* __restrict__ stats,
                            const float* __restrict__ gamma,
                            const float* __restrict__ beta,
                            float* __restrict__ ss)
{
    int c = threadIdx.x;
    float inv_n = 1.f / (float)NPIX;
    float mean = stats[c] * inv_n;
    float var  = stats[256 + c] * inv_n - mean * mean;
    float scale = gamma[c] * rsqrtf(var + EPS);
    ss[c]       = scale;
    ss[256 + c] = beta[c] - mean * scale;   // conv bias cancels under BN
}

// Normalize+ReLU. Fixed channel-octet per thread (scale/shift in regs, no
// LDS). 4 rounds per thread, 3136 blocks -> many independent memory streams.
__global__ __launch_bounds__(256) void k3_norm(
    const __hip_bfloat16* __restrict__ y, const float* __restrict__ ss,
    float* __restrict__ out)
{
    const int t   = threadIdx.x;
    const int oct = t & 31;               // channel octet
    const int pr  = t >> 5;               // pixel sub-index 0..7
    const int c0  = oct * 8;

    float4 sc0 = *(const float4*)(ss + c0);
    float4 sc1 = *(const float4*)(ss + c0 + 4);
    float4 sh0 = *(const float4*)(ss + 256 + c0);
    float4 sh1 = *(const float4*)(ss + 256 + c0 + 4);

    const uint4* yv = (const uint4*)y;
    float4* ov = (float4*)out;
    const int px0 = blockIdx.x * 32 + pr;

    uint4 d[4];
    #pragma unroll
    for (int i = 0; i < 4; ++i)
        d[i] = yv[(size_t)(px0 + i*8)*32 + oct];

    #pragma unroll
    for (int i = 0; i < 4; ++i) {
        const int px = px0 + i*8;
        float f0 = __uint_as_float((d[i].x & 0xffffu) << 16);
        float f1 = __uint_as_float(d[i].x & 0xffff0000u);
        float f2 = __uint_as_float((d[i].y & 0xffffu) << 16);
        float f3 = __uint_as_float(d[i].y & 0xffff0000u);
        float f4 = __uint_as_float((d[i].z & 0xffffu) << 16);
        float f5 = __uint_as_float(d[i].z & 0xffff0000u);
        float f6 = __uint_as_float((d[i].w & 0xffffu) << 16);
        float f7 = __uint_as_float(d[i].w & 0xffff0000u);

        float4 o0, o1;
        o0.x = fmaxf(0.f, f0 * sc0.x + sh0.x);
        o0.y = fmaxf(0.f, f1 * sc0.y + sh0.y);
        o0.z = fmaxf(0.f, f2 * sc0.z + sh0.z);
        o0.w = fmaxf(0.f, f3 * sc0.w + sh0.w);
        o1.x = fmaxf(0.f, f4 * sc1.x + sh1.x);
        o1.y = fmaxf(0.f, f5 * sc1.y + sh1.y);
        o1.z = fmaxf(0.f, f6 * sc1.z + sh1.z);
        o1.w = fmaxf(0.f, f7 * sc1.w + sh1.w);

        ov[(size_t)px*64 + oct*2]     = o0;
        ov[(size_t)px*64 + oct*2 + 1] = o1;
    }
}

extern "C" void kernel_launch(void* const* d_in, const int* in_sizes, int n_in,
                              void* d_out, int out_size, void* d_ws, size_t ws_size,
                              hipStream_t stream) {
    const float* x     = (const float*)d_in[0];
    const float* wgt   = (const float*)d_in[1];
    // d_in[2] = conv bias: cancels exactly under BN mean-subtraction -- unused
    const float* gamma = (const float*)d_in[3];
    const float* beta  = (const float*)d_in[4];
    float* out = (float*)d_out;

    float* stats = (float*)d_ws;                                   // 512 floats
    float* ss    = (float*)((char*)d_ws + 2048);                   // 512 floats
    __hip_bfloat16* y  = (__hip_bfloat16*)((char*)d_ws + 4096);    // 51.4 MB
    __hip_bfloat16* xg = (__hip_bfloat16*)((char*)d_ws + 4096 + (size_t)NPIX*CC*2);

    k0_zero<<<1, 512, 0, stream>>>(stats);
    k_pre<<<NPIX/32, 256, 0, stream>>>(x, xg);
    k1_conv<<<dim3(16, 7, BB), 256, 0, stream>>>(xg, wgt, y, stats);
    k2_finalize<<<1, 256, 0, stream>>>(stats, gamma, beta, ss);
    k3_norm<<<NPIX/32, 256, 0, stream>>>(y, ss, out);
}

// Round 3
// 236.878 us; speedup vs baseline: 1.0693x; 1.0693x over previous
//
#include <hip/hip_runtime.h>
#include <hip/hip_bf16.h>

#define BB 32
#define HH 56
#define WW 56
#define CC 256
#define NPIX (BB*HH*WW)   // 100352
#define GRP 32
#define GSZ (NPIX*8)      // 802816 bf16 elems per group slice
#define EPS 1e-5f

typedef short bf16x8 __attribute__((ext_vector_type(8)));   // 8 bf16 = 4 VGPRs
typedef float f32x4  __attribute__((ext_vector_type(4)));

__device__ __forceinline__ unsigned short f2bf(float f) {
    __hip_bfloat16 h = __float2bfloat16(f);
    return *reinterpret_cast<unsigned short*>(&h);
}

// ws layout:
//   float stats[512]        : byte 0      (sum[256], sumsq[256])
//   bf16  yg[16][NPIX][16]  : byte 4096              (51.4 MB, gp-major y)
//   bf16  xg[32][NPIX][8]   : byte 4096+51380224     (51.4 MB, group-major x)

// Relayout + downconvert: x f32 NHWC (1KB/pixel) -> xg bf16 group-major
// ([g][pix][8ch], 16B/pixel/group). Both sides DRAM-linear. LDS bridge,
// stride 260 shorts (520B): phase2 reads 2-way (free), phase1 writes 4-way.
// Block 0 also zeroes stats (k0 folded in; k1 only runs after k_pre).
__global__ __launch_bounds__(256) void k_pre(
    const float* __restrict__ x, __hip_bfloat16* __restrict__ xg,
    float* __restrict__ stats)
{
    __shared__ unsigned short lx[32*260];   // 32 pixels x 260 shorts = 16.6 KB
    const int t  = threadIdx.x;
    const int P0 = blockIdx.x * 32;

    if (blockIdx.x == 0 && t < 128) {       // zero stats (512 floats)
        *(float4*)(stats + t*4) = make_float4(0.f, 0.f, 0.f, 0.f);
    }

    #pragma unroll
    for (int r = 0; r < 8; ++r) {           // 32 pixels x 64 float4-chunks
        const int id  = r*256 + t;          // pix = id>>6, c4 = id&63
        const int pix = id >> 6;
        const int c4  = id & 63;
        float4 v = *(const float4*)(x + (size_t)(P0+pix)*CC + c4*4);
        ushort4 s;
        s.x = f2bf(v.x); s.y = f2bf(v.y); s.z = f2bf(v.z); s.w = f2bf(v.w);
        *(ushort4*)(lx + pix*260 + c4*4) = s;
    }
    __syncthreads();
    #pragma unroll
    for (int r = 0; r < 4; ++r) {           // 32 groups x 32 pixels
        const int oid = r*256 + t;          // pl = oid&31, g = oid>>5
        const int pl  = oid & 31;
        const int g   = oid >> 5;
        ushort4 a = *(const ushort4*)(lx + pl*260 + g*8);
        ushort4 c = *(const ushort4*)(lx + pl*260 + g*8 + 4);
        __hip_bfloat16* dst = xg + (size_t)g*GSZ + (size_t)(P0+pl)*8;
        *(ushort4*)dst       = a;
        *(ushort4*)(dst + 4) = c;
    }
}

// Grouped conv via bf16 MFMA. Block: one group-pair (16 out-ch), one 8-row
// band, one batch image. K packed [g0 taps + pad][g1 taps + pad] = 160
// -> 5 x mfma_f32_16x16x32_bf16 with block-diagonal operand.
// Reads xg (group-major bf16): ~900B contiguous runs per (row,group).
// Writes yg (group-pair-major): per wave each 8-pixel row = one 256B
// contiguous run in its own gp slice -> coalesced, full-line L2 writes
// (was: 32B slices per 512B pixel record = partial-line RMW storms).
__global__ __launch_bounds__(256, 5) void k1_conv(
    const __hip_bfloat16* __restrict__ xg, const float* __restrict__ wgt,
    __hip_bfloat16* __restrict__ yg, float* __restrict__ stats)
{
    __shared__ unsigned short xt[10*58*24];   // bf16 tile, padded stride (27.8 KB)
    __shared__ float bsum[16], bsq[16];

    const int gp = blockIdx.x;      // group pair 0..15 (channels gp*16..+16)
    const int hb = blockIdx.y;      // 8-row band 0..6
    const int b  = blockIdx.z;
    const int t  = threadIdx.x;
    const int h0 = hb * 8;

    if (t < 16) { bsum[t] = 0.f; bsq[t] = 0.f; }

    // ---- stage xg tile: 10 rows x 2 groups x 58 cols, one uint4 per elem
    #pragma unroll
    for (int j = 0; j < 5; ++j) {
        const int e   = j*256 + t;        // < 1160 valid
        const int col = e % 58;           // const divisor -> magic mul
        const int rg  = e / 58;           // 0..19
        const int row = rg >> 1;
        const int g   = rg & 1;
        const int hh  = h0 - 1 + row;
        const int wc  = col - 1;
        uint4 v = make_uint4(0u, 0u, 0u, 0u);
        if (e < 1160 && (unsigned)hh < HH && (unsigned)wc < WW)
            v = *(const uint4*)(xg + (size_t)(gp*2+g)*GSZ
                                   + (size_t)((b*HH + hh)*WW + wc)*8);
        if (e < 1160)
            *(uint4*)(xt + (row*58 + col)*24 + g*8) = v;
    }

    const int lane = t & 63;
    const int rp   = t >> 6;              // wave id = row-pair 0..3
    const int n    = lane & 15;           // A row (local out-ch)
    const int q    = lane >> 4;           // K-octet

    // ---- A-fragments (weights) straight from global: octet o = one tap of
    // one group-half, elements = the 8 in-ch of that tap (stride 1KB, L1-hit).
    bf16x8 wfrag[5];
    #pragma unroll
    for (int s = 0; s < 5; ++s) {
        const int o   = s*4 + q;          // octet 0..19
        const int g   = (o >= 10);
        const int tap = o - g*10;
        bf16x8 f = {0,0,0,0,0,0,0,0};
        if (tap < 9 && (n >> 3) == g) {
            #pragma unroll
            for (int e = 0; e < 8; ++e)
                f[e] = (short)f2bf(wgt[(tap*8 + e)*CC + gp*16 + n]);
        }
        wfrag[s] = f;
    }

    __syncthreads();

    const int m    = lane & 15;           // B col (pixel in 2x8 tile)
    const int rowr = rp*2 + (m >> 3);     // tile row of pixel (0..7)
    const int colb = m & 7;               // tile col within 8-col tile

    // B-fragment LDS offsets per K-step (lane octet -> tap,g)
    int aoff[5];
    #pragma unroll
    for (int s = 0; s < 5; ++s) {
        int o  = s*4 + q;
        int g  = (o >= 10);
        int tp = o - g*10;
        if (tp == 9) tp = 0;              // pad octet: A is zero, addr dontcare
        int dh = tp / 3, dw = tp - dh*3;
        aoff[s] = ((rowr + dh)*58 + colb + dw)*24 + g*8;
    }

    const int h = h0 + rowr;
    const size_t pixbase = ((size_t)(b*HH + h))*WW;
    float lsum[4] = {0.f, 0.f, 0.f, 0.f};
    float lsq[4]  = {0.f, 0.f, 0.f, 0.f};

    #pragma unroll 2
    for (int ct = 0; ct < 7; ++ct) {      // 7 col-tiles of 8 pixels
        f32x4 acc = {0.f, 0.f, 0.f, 0.f};
        #pragma unroll
        for (int s = 0; s < 5; ++s) {
            bf16x8 af = *(const bf16x8*)(xt + aoff[s] + ct*192);
            acc = __builtin_amdgcn_mfma_f32_16x16x32_bf16(wfrag[s], af, acc, 0, 0, 0);
        }
        // lane holds channels gp*16 + q*4 + 0..3 of pixel (h, ct*8+colb):
        // store into gp-major yg -> 8-pixel row = 256B contiguous per wave
        ushort4 st;
        st.x = f2bf(acc[0]); st.y = f2bf(acc[1]);
        st.z = f2bf(acc[2]); st.w = f2bf(acc[3]);
        *(ushort4*)(yg + ((size_t)gp*NPIX + pixbase + ct*8 + colb)*16 + q*4) = st;
        #pragma unroll
        for (int i = 0; i < 4; ++i) {
            lsum[i] += acc[i];
            lsq[i]  += acc[i]*acc[i];
        }
    }

    // reduce over the 16 lanes sharing this channel quad (same q)
    #pragma unroll
    for (int d = 8; d >= 1; d >>= 1) {
        #pragma unroll
        for (int i = 0; i < 4; ++i) {
            lsum[i] += __shfl_xor(lsum[i], d);
            lsq[i]  += __shfl_xor(lsq[i],  d);
        }
    }
    if (m == 0) {
        #pragma unroll
        for (int i = 0; i < 4; ++i) {
            atomicAdd(&bsum[q*4 + i], lsum[i]);
            atomicAdd(&bsq[q*4 + i],  lsq[i]);
        }
    }
    __syncthreads();
    if (t < 16) {
        atomicAdd(&stats[gp*16 + t],       bsum[t]);
        atomicAdd(&stats[256 + gp*16 + t], bsq[t]);
    }
}

// Normalize+ReLU with the gp-major -> pixel-major transpose via LDS.
// Reads yg in 1KB-contiguous chunks per gp slice; writes out f32 NHWC
// 1KB-contiguous per pixel. scale/shift computed inline from stats
// (k2 folded in: 8 rsqrt per thread, stats/gamma/beta are L2-broadcast).
__global__ __launch_bounds__(256) void k3_norm(
    const __hip_bfloat16* __restrict__ yg, const float* __restrict__ stats,
    const float* __restrict__ gamma, const float* __restrict__ beta,
    float* __restrict__ out)
{
    __shared__ unsigned short lx[32*260];   // 32 pixels x 256ch (+pad) = 16.6 KB
    const int t  = threadIdx.x;
    const int P0 = blockIdx.x * 32;

    // ---- load 16 gp slices x 32 pixels (32B each) into LDS pixel-major
    #pragma unroll
    for (int r = 0; r < 2; ++r) {
        const int id = r*256 + t;           // gp = id>>5, pl = id&31
        const int g  = id >> 5;
        const int pl = id & 31;
        const __hip_bfloat16* src = yg + ((size_t)g*NPIX + P0 + pl)*16;
        uint4 v0 = *(const uint4*)(src);
        uint4 v1 = *(const uint4*)(src + 8);
        *(uint4*)(lx + pl*260 + g*16)     = v0;
        *(uint4*)(lx + pl*260 + g*16 + 8) = v1;
    }

    // ---- per-thread scale/shift for its channel octet (overlaps LDS fill)
    const int oct = t & 31;               // channel octet
    const int pr  = t >> 5;               // pixel sub-index 0..7
    const int c0  = oct * 8;
    const float inv_n = 1.f / (float)NPIX;
    float sc[8], sh[8];
    #pragma unroll
    for (int i = 0; i < 8; ++i) {
        float mean = stats[c0+i] * inv_n;
        float var  = stats[256+c0+i] * inv_n - mean*mean;
        float s    = gamma[c0+i] * rsqrtf(var + EPS);
        sc[i] = s;
        sh[i] = beta[c0+i] - mean * s;    // conv bias cancels under BN
    }
    __syncthreads();

    #pragma unroll
    for (int i = 0; i < 4; ++i) {
        const int pl = pr + i*8;
        ushort4 a = *(const ushort4*)(lx + pl*260 + c0);
        ushort4 c = *(const ushort4*)(lx + pl*260 + c0 + 4);
        float f0 = __uint_as_float((unsigned)a.x << 16);
        float f1 = __uint_as_float((unsigned)a.y << 16);
        float f2 = __uint_as_float((unsigned)a.z << 16);
        float f3 = __uint_as_float((unsigned)a.w << 16);
        float f4 = __uint_as_float((unsigned)c.x << 16);
        float f5 = __uint_as_float((unsigned)c.y << 16);
        float f6 = __uint_as_float((unsigned)c.z << 16);
        float f7 = __uint_as_float((unsigned)c.w << 16);

        float4 o0, o1;
        o0.x = fmaxf(0.f, f0 * sc[0] + sh[0]);
        o0.y = fmaxf(0.f, f1 * sc[1] + sh[1]);
        o0.z = fmaxf(0.f, f2 * sc[2] + sh[2]);
        o0.w = fmaxf(0.f, f3 * sc[3] + sh[3]);
        o1.x = fmaxf(0.f, f4 * sc[4] + sh[4]);
        o1.y = fmaxf(0.f, f5 * sc[5] + sh[5]);
        o1.z = fmaxf(0.f, f6 * sc[6] + sh[6]);
        o1.w = fmaxf(0.f, f7 * sc[7] + sh[7]);

        float* dst = out + (size_t)(P0 + pl)*CC + c0;
        *(float4*)(dst)     = o0;
        *(float4*)(dst + 4) = o1;
    }
}

extern "C" void kernel_launch(void* const* d_in, const int* in_sizes, int n_in,
                              void* d_out, int out_size, void* d_ws, size_t ws_size,
                              hipStream_t stream) {
    const float* x     = (const float*)d_in[0];
    const float* wgt   = (const float*)d_in[1];
    // d_in[2] = conv bias: cancels exactly under BN mean-subtraction -- unused
    const float* gamma = (const float*)d_in[3];
    const float* beta  = (const float*)d_in[4];
    float* out = (float*)d_out;

    float* stats = (float*)d_ws;                                   // 512 floats
    __hip_bfloat16* yg = (__hip_bfloat16*)((char*)d_ws + 4096);    // 51.4 MB
    __hip_bfloat16* xg = (__hip_bfloat16*)((char*)d_ws + 4096 + (size_t)NPIX*CC*2);

    k_pre<<<NPIX/32, 256, 0, stream>>>(x, xg, stats);
    k1_conv<<<dim3(16, 7, BB), 256, 0, stream>>>(xg, wgt, yg, stats);
    k3_norm<<<NPIX/32, 256, 0, stream>>>(yg, stats, gamma, beta, out);
}

// Round 6
// 232.053 us; speedup vs baseline: 1.0916x; 1.0208x over previous
//
#include <hip/hip_runtime.h>
#include <hip/hip_bf16.h>

#define BB 32
#define HH 56
#define WW 56
#define CC 256
#define NPIX (BB*HH*WW)   // 100352
#define GRP 32
#define GSZ (NPIX*8)      // 802816 bf16 elems per group slice
#define EPS 1e-5f

typedef short bf16x8 __attribute__((ext_vector_type(8)));   // 8 bf16 = 4 VGPRs
typedef float f32x4  __attribute__((ext_vector_type(4)));

__device__ __forceinline__ unsigned short f2bf(float f) {
    __hip_bfloat16 h = __float2bfloat16(f);
    return *reinterpret_cast<unsigned short*>(&h);
}

// ws layout:
//   float stats[512]        : byte 0      (sum[256], sumsq[256])
//   bf16  yg[16][NPIX][16]  : byte 4096               (51.4 MB, gp-major y)
//   bf16  xg[32][NPIX][8]   : byte 4096+51380224      (51.4 MB, group-major x)
//   bf16  wT[256][80]       : byte 4096+102760448     (40 KB, conv-ready wgt)
//
// (Cooperative single-kernel fusion crashed the container -- coop launch is
// not graph-capture-safe here. Round-5 run died with NO diagnostic on this
// exact statically-audited source: attributing to infra; resubmitting.)

// Relayout + downconvert: x f32 NHWC (1KB/pixel) -> xg bf16 group-major
// ([g][pix][8ch], 16B/pixel/group). Both sides DRAM-linear. LDS bridge,
// stride 260 shorts (520B). Block 0 additionally zeroes stats and builds
// wT: weights transposed to [gp*16+n][tap][ci] so k1 reads each MFMA
// fragment as ONE b128 load (was 40 scalar loads per thread).
__global__ __launch_bounds__(256) void k_pre(
    const float* __restrict__ x, const float* __restrict__ wgt,
    __hip_bfloat16* __restrict__ xg, unsigned short* __restrict__ wT,
    float* __restrict__ stats)
{
    __shared__ unsigned short lx[32*260];   // 32 pixels x 260 shorts = 16.6 KB
    const int t  = threadIdx.x;
    const int P0 = blockIdx.x * 32;

    if (blockIdx.x == 0) {
        if (t < 128)                        // zero stats (512 floats)
            *(float4*)(stats + t*4) = make_float4(0.f, 0.f, 0.f, 0.f);
        // weight transpose: thread t = gp*16+n owns one 80-short row.
        // Reads are lane-coalesced (consecutive t -> consecutive floats).
        const int cw = t;                   // gp*16 + n
        unsigned short* dst = wT + (size_t)cw*80;
        #pragma unroll
        for (int tap = 0; tap < 9; ++tap) {
            ushort4 s4;
            s4.x = f2bf(wgt[(tap*8+0)*CC + cw]);
            s4.y = f2bf(wgt[(tap*8+1)*CC + cw]);
            s4.z = f2bf(wgt[(tap*8+2)*CC + cw]);
            s4.w = f2bf(wgt[(tap*8+3)*CC + cw]);
            *(ushort4*)(dst + tap*8) = s4;
            s4.x = f2bf(wgt[(tap*8+4)*CC + cw]);
            s4.y = f2bf(wgt[(tap*8+5)*CC + cw]);
            s4.z = f2bf(wgt[(tap*8+6)*CC + cw]);
            s4.w = f2bf(wgt[(tap*8+7)*CC + cw]);
            *(ushort4*)(dst + tap*8 + 4) = s4;
        }
    }

    #pragma unroll
    for (int r = 0; r < 8; ++r) {           // 32 pixels x 64 float4-chunks
        const int id  = r*256 + t;          // pix = id>>6, c4 = id&63
        const int pix = id >> 6;
        const int c4  = id & 63;
        float4 v = *(const float4*)(x + (size_t)(P0+pix)*CC + c4*4);
        ushort4 s;
        s.x = f2bf(v.x); s.y = f2bf(v.y); s.z = f2bf(v.z); s.w = f2bf(v.w);
        *(ushort4*)(lx + pix*260 + c4*4) = s;
    }
    __syncthreads();
    #pragma unroll
    for (int r = 0; r < 4; ++r) {           // 32 groups x 32 pixels
        const int oid = r*256 + t;          // pl = oid&31, g = oid>>5
        const int pl  = oid & 31;
        const int g   = oid >> 5;
        ushort4 a = *(const ushort4*)(lx + pl*260 + g*8);
        ushort4 c = *(const ushort4*)(lx + pl*260 + g*8 + 4);
        __hip_bfloat16* dst = xg + (size_t)g*GSZ + (size_t)(P0+pl)*8;
        *(ushort4*)dst       = a;
        *(ushort4*)(dst + 4) = c;
    }
}

// Grouped conv via bf16 MFMA. Block: one group-pair (16 out-ch), one 8-row
// band, one batch image. K packed [g0 taps + pad][g1 taps + pad] = 160
// -> 5 x mfma_f32_16x16x32_bf16 with block-diagonal operand.
// Reads xg (group-major bf16): ~900B contiguous runs per (row,group).
// Writes yg (group-pair-major): 8-pixel rows = 256B contiguous per wave.
// Weights from wT: one aligned b128 per fragment (L2-broadcast), total
// <=5 VMEM per thread vs 40 scalar loads previously.
__global__ __launch_bounds__(256, 5) void k1_conv(
    const __hip_bfloat16* __restrict__ xg, const unsigned short* __restrict__ wT,
    __hip_bfloat16* __restrict__ yg, float* __restrict__ stats)
{
    __shared__ unsigned short xt[10*58*24];   // bf16 tile, padded stride (27.8 KB)
    __shared__ float bsum[16], bsq[16];

    const int gp = blockIdx.x;      // group pair 0..15 (channels gp*16..+16)
    const int hb = blockIdx.y;      // 8-row band 0..6
    const int b  = blockIdx.z;
    const int t  = threadIdx.x;
    const int h0 = hb * 8;

    if (t < 16) { bsum[t] = 0.f; bsq[t] = 0.f; }

    // ---- stage xg tile: 10 rows x 2 groups x 58 cols, one uint4 per elem
    #pragma unroll
    for (int j = 0; j < 5; ++j) {
        const int e   = j*256 + t;        // < 1160 valid
        const int col = e % 58;           // const divisor -> magic mul
        const int rg  = e / 58;           // 0..19
        const int row = rg >> 1;
        const int g   = rg & 1;
        const int hh  = h0 - 1 + row;
        const int wc  = col - 1;
        uint4 v = make_uint4(0u, 0u, 0u, 0u);
        if (e < 1160 && (unsigned)hh < HH && (unsigned)wc < WW)
            v = *(const uint4*)(xg + (size_t)(gp*2+g)*GSZ
                                   + (size_t)((b*HH + hh)*WW + wc)*8);
        if (e < 1160)
            *(uint4*)(xt + (row*58 + col)*24 + g*8) = v;
    }

    const int lane = t & 63;
    const int rp   = t >> 6;              // wave id = row-pair 0..3
    const int n    = lane & 15;           // A row (local out-ch)
    const int q    = lane >> 4;           // K-octet

    // ---- A-fragments (weights): one b128 per fragment from wT
    const unsigned short* wrow = wT + (size_t)(gp*16 + n)*80;
    bf16x8 wfrag[5];
    #pragma unroll
    for (int s = 0; s < 5; ++s) {
        const int o   = s*4 + q;          // octet 0..19
        const int g   = (o >= 10);
        const int tap = o - g*10;
        bf16x8 f = {0,0,0,0,0,0,0,0};
        if (tap < 9 && (n >> 3) == g)
            f = *(const bf16x8*)(wrow + tap*8);
        wfrag[s] = f;
    }

    __syncthreads();

    const int m    = lane & 15;           // B col (pixel in 2x8 tile)
    const int rowr = rp*2 + (m >> 3);     // tile row of pixel (0..7)
    const int colb = m & 7;               // tile col within 8-col tile

    // B-fragment LDS offsets per K-step (lane octet -> tap,g)
    int aoff[5];
    #pragma unroll
    for (int s = 0; s < 5; ++s) {
        int o  = s*4 + q;
        int g  = (o >= 10);
        int tp = o - g*10;
        if (tp == 9) tp = 0;              // pad octet: A is zero, addr dontcare
        int dh = tp / 3, dw = tp - dh*3;
        aoff[s] = ((rowr + dh)*58 + colb + dw)*24 + g*8;
    }

    const int h = h0 + rowr;
    const size_t pixbase = ((size_t)(b*HH + h))*WW;
    float lsum[4] = {0.f, 0.f, 0.f, 0.f};
    float lsq[4]  = {0.f, 0.f, 0.f, 0.f};

    #pragma unroll 2
    for (int ct = 0; ct < 7; ++ct) {      // 7 col-tiles of 8 pixels
        f32x4 acc = {0.f, 0.f, 0.f, 0.f};
        #pragma unroll
        for (int s = 0; s < 5; ++s) {
            bf16x8 af = *(const bf16x8*)(xt + aoff[s] + ct*192);
            acc = __builtin_amdgcn_mfma_f32_16x16x32_bf16(wfrag[s], af, acc, 0, 0, 0);
        }
        // lane holds channels gp*16 + q*4 + 0..3 of pixel (h, ct*8+colb):
        // store into gp-major yg -> 8-pixel row = 256B contiguous per wave
        ushort4 st;
        st.x = f2bf(acc[0]); st.y = f2bf(acc[1]);
        st.z = f2bf(acc[2]); st.w = f2bf(acc[3]);
        *(ushort4*)(yg + ((size_t)gp*NPIX + pixbase + ct*8 + colb)*16 + q*4) = st;
        #pragma unroll
        for (int i = 0; i < 4; ++i) {
            lsum[i] += acc[i];
            lsq[i]  += acc[i]*acc[i];
        }
    }

    // reduce over the 16 lanes sharing this channel quad (same q)
    #pragma unroll
    for (int d = 8; d >= 1; d >>= 1) {
        #pragma unroll
        for (int i = 0; i < 4; ++i) {
            lsum[i] += __shfl_xor(lsum[i], d);
            lsq[i]  += __shfl_xor(lsq[i],  d);
        }
    }
    if (m == 0) {
        #pragma unroll
        for (int i = 0; i < 4; ++i) {
            atomicAdd(&bsum[q*4 + i], lsum[i]);
            atomicAdd(&bsq[q*4 + i],  lsq[i]);
        }
    }
    __syncthreads();
    if (t < 16) {
        atomicAdd(&stats[gp*16 + t],       bsum[t]);
        atomicAdd(&stats[256 + gp*16 + t], bsq[t]);
    }
}

// Normalize+ReLU with the gp-major -> pixel-major transpose via LDS.
// Reads yg in 1KB-contiguous chunks per gp slice; writes out f32 NHWC
// 1KB-contiguous per pixel. scale/shift computed inline from stats.
__global__ __launch_bounds__(256) void k3_norm(
    const __hip_bfloat16* __restrict__ yg, const float* __restrict__ stats,
    const float* __restrict__ gamma, const float* __restrict__ beta,
    float* __restrict__ out)
{
    __shared__ unsigned short lx[32*260];   // 32 pixels x 256ch (+pad) = 16.6 KB
    const int t  = threadIdx.x;
    const int P0 = blockIdx.x * 32;

    // ---- load 16 gp slices x 32 pixels (32B each) into LDS pixel-major
    #pragma unroll
    for (int r = 0; r < 2; ++r) {
        const int id = r*256 + t;           // gp = id>>5, pl = id&31
        const int g  = id >> 5;
        const int pl = id & 31;
        const __hip_bfloat16* src = yg + ((size_t)g*NPIX + P0 + pl)*16;
        uint4 v0 = *(const uint4*)(src);
        uint4 v1 = *(const uint4*)(src + 8);
        *(uint4*)(lx + pl*260 + g*16)     = v0;
        *(uint4*)(lx + pl*260 + g*16 + 8) = v1;
    }

    // ---- per-thread scale/shift for its channel octet (overlaps LDS fill)
    const int oct = t & 31;               // channel octet
    const int pr  = t >> 5;               // pixel sub-index 0..7
    const int c0  = oct * 8;
    const float inv_n = 1.f / (float)NPIX;
    float sc[8], sh[8];
    #pragma unroll
    for (int i = 0; i < 8; ++i) {
        float mean = stats[c0+i] * inv_n;
        float var  = stats[256+c0+i] * inv_n - mean*mean;
        float s    = gamma[c0+i] * rsqrtf(var + EPS);
        sc[i] = s;
        sh[i] = beta[c0+i] - mean * s;    // conv bias cancels under BN
    }
    __syncthreads();

    #pragma unroll
    for (int i = 0; i < 4; ++i) {
        const int pl = pr + i*8;
        ushort4 a = *(const ushort4*)(lx + pl*260 + c0);
        ushort4 c = *(const ushort4*)(lx + pl*260 + c0 + 4);
        float f0 = __uint_as_float((unsigned)a.x << 16);
        float f1 = __uint_as_float((unsigned)a.y << 16);
        float f2 = __uint_as_float((unsigned)a.z << 16);
        float f3 = __uint_as_float((unsigned)a.w << 16);
        float f4 = __uint_as_float((unsigned)c.x << 16);
        float f5 = __uint_as_float((unsigned)c.y << 16);
        float f6 = __uint_as_float((unsigned)c.z << 16);
        float f7 = __uint_as_float((unsigned)c.w << 16);

        float4 o0, o1;
        o0.x = fmaxf(0.f, f0 * sc[0] + sh[0]);
        o0.y = fmaxf(0.f, f1 * sc[1] + sh[1]);
        o0.z = fmaxf(0.f, f2 * sc[2] + sh[2]);
        o0.w = fmaxf(0.f, f3 * sc[3] + sh[3]);
        o1.x = fmaxf(0.f, f4 * sc[4] + sh[4]);
        o1.y = fmaxf(0.f, f5 * sc[5] + sh[5]);
        o1.z = fmaxf(0.f, f6 * sc[6] + sh[6]);
        o1.w = fmaxf(0.f, f7 * sc[7] + sh[7]);

        float* dst = out + (size_t)(P0 + pl)*CC + c0;
        *(float4*)(dst)     = o0;
        *(float4*)(dst + 4) = o1;
    }
}

extern "C" void kernel_launch(void* const* d_in, const int* in_sizes, int n_in,
                              void* d_out, int out_size, void* d_ws, size_t ws_size,
                              hipStream_t stream) {
    const float* x     = (const float*)d_in[0];
    const float* wgt   = (const float*)d_in[1];
    // d_in[2] = conv bias: cancels exactly under BN mean-subtraction -- unused
    const float* gamma = (const float*)d_in[3];
    const float* beta  = (const float*)d_in[4];
    float* out = (float*)d_out;

    float* stats = (float*)d_ws;                                   // 512 floats
    __hip_bfloat16* yg = (__hip_bfloat16*)((char*)d_ws + 4096);    // 51.4 MB
    __hip_bfloat16* xg = (__hip_bfloat16*)((char*)d_ws + 4096 + (size_t)NPIX*CC*2);
    unsigned short* wT = (unsigned short*)((char*)d_ws + 4096 + 2*(size_t)NPIX*CC*2);

    k_pre<<<NPIX/32, 256, 0, stream>>>(x, wgt, xg, wT, stats);
    k1_conv<<<dim3(16, 7, BB), 256, 0, stream>>>(xg, wT, yg, stats);
    k3_norm<<<NPIX/32, 256, 0, stream>>>(yg, stats, gamma, beta, out);
}